// Round 8
// baseline (346.403 us; speedup 1.0000x reference)
//
#include <hip/hip_runtime.h>

#define D 512
#define NNODES 1365
#define OUT_STRIDE (NNODES * D)   // 698880 floats per batch row

typedef __attribute__((ext_vector_type(4))) float f32x4;
typedef __attribute__((ext_vector_type(8))) short bf16x8;

union U4 { unsigned u[4]; bf16x8 v; };

__device__ __forceinline__ unsigned cvt_pk_bf16(float s0, float s1) {
    unsigned r;
    asm volatile("v_cvt_pk_bf16_f32 %0, %1, %2" : "=v"(r) : "v"(s0), "v"(s1));
    return r;
}

__device__ __forceinline__ void gld_lds16(const void* g, void* l) {
    __builtin_amdgcn_global_load_lds(
        (const __attribute__((address_space(1))) unsigned*)g,
        (__attribute__((address_space(3))) unsigned*)l, 16, 0, 0);
}

template<int N> __device__ __forceinline__ void waitV() {
    asm volatile("s_waitcnt vmcnt(%0)" :: "i"(N) : "memory");
}

// split-bf16 fp32 MFMA emulation: AhBh + AlBh + AhBl
__device__ __forceinline__ void mfma3(bf16x8 ah, bf16x8 al, f32x4 b0, f32x4 b1,
                                      f32x4& acc) {
    U4 bH, bL;
    float xs[8] = {b0[0],b0[1],b0[2],b0[3],b1[0],b1[1],b1[2],b1[3]};
    #pragma unroll
    for (int k = 0; k < 4; ++k) {
        unsigned hh = cvt_pk_bf16(xs[2*k], xs[2*k+1]);
        float f0 = __uint_as_float(hh << 16);
        float f1 = __uint_as_float(hh & 0xFFFF0000u);
        bL.u[k] = cvt_pk_bf16(xs[2*k] - f0, xs[2*k+1] - f1);
        bH.u[k] = hh;
    }
    acc = __builtin_amdgcn_mfma_f32_16x16x32_bf16(ah, bH.v, acc, 0,0,0);
    acc = __builtin_amdgcn_mfma_f32_16x16x32_bf16(al, bH.v, acc, 0,0,0);
    acc = __builtin_amdgcn_mfma_f32_16x16x32_bf16(ah, bL.v, acc, 0,0,0);
}

__device__ __forceinline__ void build_afrags(const float* arow, int m4,
                                             bf16x8* aH, bf16x8* aL) {
    #pragma unroll
    for (int j = 0; j < 16; ++j) {
        const float* p = arow + j * 32 + m4 * 8;
        f32x4 x0 = *(const f32x4*)p;
        f32x4 x1 = *(const f32x4*)(p + 4);
        float xs[8] = {x0[0],x0[1],x0[2],x0[3],x1[0],x1[1],x1[2],x1[3]};
        U4 h, l;
        #pragma unroll
        for (int k = 0; k < 4; ++k) {
            unsigned hh = cvt_pk_bf16(xs[2*k], xs[2*k+1]);
            float f0 = __uint_as_float(hh << 16);
            float f1 = __uint_as_float(hh & 0xFFFF0000u);
            l.u[k] = cvt_pk_bf16(xs[2*k] - f0, xs[2*k+1] - f1);
            h.u[k] = hh;
        }
        aH[j] = h.v; aL[j] = l.v;
    }
}

// ========== big levels (4,5): 2-wave blocks, 1KB-contiguous DMA chunks ======
// Chunk = 16 rows x 1KB K-half (16 insts, each 1KB linear). Group = 16 rows
// = 2 chunks (K-halves), accumulated into one 16x16 C-tile per wave. Each
// DRAM 2KB row touched in 2 passes (vs 4 in the 512B scheme). Per-wave
// dbuf: buf0=half0, buf1=half1. Counted waits: 16 / 20/16 steady / 20,0 tail
// (16 loads per chunk, 4 epilogue stores accounted). LDS 64KB -> 2 blocks/CU.
template<int NGW>
__global__ __launch_bounds__(128)
void stream_kernel(const float* __restrict__ W, const float* __restrict__ bias,
                   const float* __restrict__ src, float* __restrict__ out,
                   int node_start, int bpn)
{
    __shared__ float Wt[2][2][4096];        // [wave][buf][16KB]
    __shared__ float bias_lds[32 * NGW];

    const int tid  = threadIdx.x;
    const int w    = tid >> 6;
    const int lane = tid & 63;
    const int m4   = lane >> 4;
    const int c0   = lane & 15;

    const int node  = node_start + blockIdx.x / bpn;
    const int nbase = (blockIdx.x % bpn) * (32 * NGW);
    const char* Wn  = (const char*)(W + (size_t)node * (D * D));

    for (int t = tid; t < 32 * NGW; t += 128)
        bias_lds[t] = bias[(size_t)node * D + nbase + t];

    const float* arow = src + (size_t)c0 * OUT_STRIDE
                            + (size_t)((node - 1) >> 2) * D;
    bf16x8 aH[16], aL[16];
    build_afrags(arow, m4, aH, aL);
    __syncthreads();   // bias visible; all prologue vmem drained

    // DMA: inst i = row i's 1KB window; source XOR-permuted within the
    // window ((i&7)<<4 involution), LDS dest linear at i*1024.
    const int u16 = lane * 16;
    auto issue = [&](const char* gchunk, int buf) {
        char* ldst = (char*)&Wt[w][buf][0];
        #pragma unroll
        for (int i = 0; i < 16; ++i)
            gld_lds16(gchunk + (size_t)i * 2048 + (u16 ^ ((i & 7) << 4)),
                      ldst + i * 1024);
    };

    const int rsw = (c0 & 7) << 4;
    const char* tb0 = (const char*)&Wt[w][0][0] + c0 * 1024;
    const char* tb1 = (const char*)&Wt[w][1][0] + c0 * 1024;

    auto half0 = [&](f32x4& acc) {
        #pragma unroll
        for (int ks = 0; ks < 8; ++ks) {
            f32x4 b0 = *(const f32x4*)(tb0 + ((ks * 128 + m4 * 32)      ^ rsw));
            f32x4 b1 = *(const f32x4*)(tb0 + ((ks * 128 + m4 * 32 + 16) ^ rsw));
            mfma3(aH[ks], aL[ks], b0, b1, acc);
        }
    };
    auto half1 = [&](f32x4& acc) {
        #pragma unroll
        for (int ks = 0; ks < 8; ++ks) {
            f32x4 b0 = *(const f32x4*)(tb1 + ((ks * 128 + m4 * 32)      ^ rsw));
            f32x4 b1 = *(const f32x4*)(tb1 + ((ks * 128 + m4 * 32 + 16) ^ rsw));
            mfma3(aH[8 + ks], aL[8 + ks], b0, b1, acc);
        }
    };

    const size_t GSTRIDE = 65536;           // wave-group stride: 32 rows
    const char* gb = Wn + (size_t)(nbase + w * 16) * 2048;
    issue(gb,        0);                    // group0 half0
    issue(gb + 1024, 1);                    // group0 half1

    float* op = out + (size_t)node * D + nbase + w * 16 + c0;
    const float* bl = &bias_lds[w * 16 + c0];

    auto epi = [&](f32x4& acc) {
        const float bv = *bl;
        #pragma unroll
        for (int i = 0; i < 4; ++i)
            op[(size_t)(m4 * 4 + i) * OUT_STRIDE] = fmaxf(acc[i] + bv, 0.f);
        op += 32; bl += 32;
    };

    {   // group 0 (peeled)
        f32x4 acc = {0.f,0.f,0.f,0.f};
        waitV<16>(); half0(acc);            // drain A0; B0 in flight
        issue(gb + GSTRIDE, 0);
        waitV<16>(); half1(acc);            // drain B0; A1 in flight
        epi(acc);
        issue(gb + GSTRIDE + 1024, 1);
        gb += GSTRIDE;
    }
    #pragma clang loop unroll(disable)
    for (int g = 1; g < NGW - 1; ++g) {     // steady: 36 -> 20 -> 36 -> ...
        f32x4 acc = {0.f,0.f,0.f,0.f};
        waitV<20>(); half0(acc);            // drain A_g; st+B_g remain
        issue(gb + GSTRIDE, 0);
        waitV<16>(); half1(acc);            // drain st+B_g; A' remains
        epi(acc);
        issue(gb + GSTRIDE + 1024, 1);
        gb += GSTRIDE;
    }
    {   // last group
        f32x4 acc = {0.f,0.f,0.f,0.f};
        waitV<20>(); half0(acc);
        waitV<0>();  half1(acc);
        epi(acc);
    }
}

// ========== small levels (0-3): R6 kernel, verbatim (proven) ================
template<bool RELU>
__global__ __launch_bounds__(256, 2)
void node_kernel(const float* __restrict__ W, const float* __restrict__ bias,
                 const float* __restrict__ src_base, float* __restrict__ out,
                 int node_start, int bpn, int ngroups, int src_stride)
{
    __shared__ float Wt[4][2][2048];
    __shared__ float bias_lds[512];

    const int tid  = threadIdx.x;
    const int w    = tid >> 6;
    const int lane = tid & 63;
    const int m4   = lane >> 4;
    const int c0   = lane & 15;

    const int node  = node_start + blockIdx.x / bpn;
    const int nbase = (blockIdx.x % bpn) * (64 * ngroups);
    const char* Wn  = (const char*)(W + (size_t)node * (D * D));

    for (int t = tid; t < 64 * ngroups; t += 256)
        bias_lds[t] = bias[(size_t)node * D + nbase + t];

    const float* arow = (RELU ? src_base + (size_t)((node - 1) >> 2) * D
                              : src_base) + (size_t)c0 * src_stride;
    bf16x8 aH[16], aL[16];
    build_afrags(arow, m4, aH, aL);
    __syncthreads();

    int loffs[8];
    const int rr  = lane >> 5;
    const int off = (lane & 31) * 16;
    #pragma unroll
    for (int i = 0; i < 8; ++i) {
        const int r = i * 2 + rr;
        loffs[i] = r * 2048 + (off ^ ((r & 7) << 4));
    }
    auto issue = [&](const char* gsrc, int buf) {
        char* ldst = (char*)&Wt[w][buf][0];
        #pragma unroll
        for (int i = 0; i < 8; ++i)
            gld_lds16(gsrc + loffs[i], ldst + i * 1024);
    };

    const int rsw = (c0 & 7) << 4;
    const int po0 = c0 * 512 + ((m4 * 32)      ^ rsw);
    const int po1 = c0 * 512 + ((m4 * 32 + 16) ^ rsw);

    const size_t GRP = (size_t)64 * 2048;
    const char* gcur = Wn + (size_t)(nbase + w * 16) * 2048;
    issue(gcur,       0);
    issue(gcur + 512, 1);

    float* optr = out + (size_t)node * D + nbase + w * 16 + c0;
    const float* blds = &bias_lds[w * 16 + c0];

    auto compute_q = [&](auto qc, f32x4& acc) {
        constexpr int Q = decltype(qc)::value;
        const char* tb = (const char*)&Wt[w][Q & 1][0];
        #pragma unroll
        for (int ks = 0; ks < 4; ++ks) {
            f32x4 b0 = *(const f32x4*)(tb + po0 + ks * 128);
            f32x4 b1 = *(const f32x4*)(tb + po1 + ks * 128);
            mfma3(aH[Q*4+ks], aL[Q*4+ks], b0, b1, acc);
        }
    };

    #pragma clang loop unroll(disable)
    for (int g = 0; g < ngroups; ++g) {
        const bool last = (g == ngroups - 1);
        const char* gnext = gcur + GRP;
        f32x4 acc = {0.f,0.f,0.f,0.f};

        waitV<8>();
        compute_q(std::integral_constant<int,0>{}, acc);
        issue(gcur + 1024, 0);
        waitV<8>();
        compute_q(std::integral_constant<int,1>{}, acc);
        issue(gcur + 1536, 1);
        waitV<8>();
        compute_q(std::integral_constant<int,2>{}, acc);
        if (!last) issue(gnext, 0);
        if (last) waitV<0>(); else waitV<8>();
        compute_q(std::integral_constant<int,3>{}, acc);

        const float bv = *blds;
        #pragma unroll
        for (int i = 0; i < 4; ++i) {
            float v = acc[i] + bv;
            if (RELU) v = fmaxf(v, 0.f);
            optr[(size_t)(m4 * 4 + i) * OUT_STRIDE] = v;
        }
        if (!last) issue(gnext + 512, 1);

        gcur = gnext; optr += 64; blds += 64;
    }
}

extern "C" void kernel_launch(void* const* d_in, const int* in_sizes, int n_in,
                              void* d_out, int out_size, void* d_ws, size_t ws_size,
                              hipStream_t stream) {
    const float* inputs = (const float*)d_in[0];   // (16, 512)
    const float* W      = (const float*)d_in[1];   // (1365, 512, 512)
    const float* bias   = (const float*)d_in[2];   // (1365, 512)
    float* out          = (float*)d_out;           // (16, 1365*512)

    node_kernel<false><<<   8, 256, 0, stream>>>(W, bias, inputs, out,   0, 8, 1, D);
    node_kernel<true ><<<  32, 256, 0, stream>>>(W, bias, out,    out,   1, 8, 1, OUT_STRIDE);
    node_kernel<true ><<< 128, 256, 0, stream>>>(W, bias, out,    out,   5, 8, 1, OUT_STRIDE);
    node_kernel<true ><<< 512, 256, 0, stream>>>(W, bias, out,    out,  21, 8, 1, OUT_STRIDE);
    // big levels: 2-wave blocks; lvl4 = 2 blocks/node (8 groups/wave),
    // lvl5 = 1 block/node (16 groups/wave)
    stream_kernel< 8><<< 512, 128, 0, stream>>>(W, bias, out, out,  85, 2);
    stream_kernel<16><<<1024, 128, 0, stream>>>(W, bias, out, out, 341, 1);
}